// Round 8
// baseline (503.333 us; speedup 1.0000x reference)
//
#include <hip/hip_runtime.h>
#include <hip/hip_cooperative_groups.h>

namespace cg = cooperative_groups;

#define HIDDEN 64
#define NB 32
#define HSTR 72        // LDS H-tile row stride in shorts: %8==0 (16B align for b128)
#define CS_THREADS 512 // coop scan/scatter block (8 waves -> trivially co-resident)
#define CS_BLOCKS 256  // 1 block/CU

typedef __attribute__((ext_vector_type(8))) short bf16x8;
typedef __attribute__((ext_vector_type(4))) short s16x4;
typedef __attribute__((ext_vector_type(4))) float f32x4;
typedef __attribute__((ext_vector_type(8))) unsigned short u16x8;

// ---- bf16 helpers ----
// Native cast: compiler lowers float->__bf16 to v_cvt_pk_bf16_f32 (RNE) --
// ~4x fewer VALU ops than the manual round-bit sequence (guide T12/m240:
// "don't hand-write cvt_pk; the compiler handles scalar casts").
static __device__ __forceinline__ unsigned short f2bf(float x) {
    union { __bf16 b; unsigned short u; } v;
    v.b = (__bf16)x;
    return v.u;
}
static __device__ __forceinline__ float bf2f(unsigned short s) {
    union { unsigned u; float f; } v; v.u = ((unsigned)s) << 16;
    return v.f;
}
// unpack an interleaved {ws,wv} dword: lo short = ws, hi short = wv
static __device__ __forceinline__ float lo_bf(unsigned u) {
    union { unsigned u; float f; } v; v.u = u << 16; return v.f;
}
static __device__ __forceinline__ float hi_bf(unsigned u) {
    union { unsigned u; float f; } v; v.u = u & 0xffff0000u; return v.f;
}

// ---------------------------------------------------------------------------
// Feature pack (x2 vectorized), PURE pack: histogram moved into the coop
// kernel. Thread handles elements {2i, 2i+1} (same node row), float2 loads,
// one 16 B feat store.
// ---------------------------------------------------------------------------
__global__ __launch_bounds__(256) void featpack_kernel(
    const float* __restrict__ scalar,     // [N,64]
    const float* __restrict__ vector,     // [N,3,64]
    u16x8* __restrict__ featv,            // [N*32] = feat as 16 B packs
    int total)
{
    const int idx   = blockIdx.x * 256 + threadIdx.x;
    const int base2 = idx * 2;
    if (base2 >= total) return;
    const int n = base2 >> 6, l = base2 & 63;
    const float* vp = vector + (size_t)n * 192 + l;
    const float2 s2 = *(const float2*)(scalar + base2);
    const float2 w0 = *(const float2*)(vp);
    const float2 w1 = *(const float2*)(vp + 64);
    const float2 w2 = *(const float2*)(vp + 128);
    u16x8 o;
    o[0] = f2bf(s2.x); o[1] = f2bf(w0.x); o[2] = f2bf(w1.x); o[3] = f2bf(w2.x);
    o[4] = f2bf(s2.y); o[5] = f2bf(w0.y); o[6] = f2bf(w1.y); o[7] = f2bf(w2.y);
    featv[idx] = o;
}

// ---------------------------------------------------------------------------
// Cooperative zero + hist + scan + scatter: replaces 5 dispatches
// (memset, hist, scan1/2/3, scatter). All phases are either tiny (50k scan)
// or grid-strided over 131k threads (hist/scatter: ~4 edges/thread).
// 256 blocks x 512 threads = 8 waves/CU, co-residency guaranteed.
// Requires N < CS_BLOCKS*CS_THREADS (= 131072).
// ---------------------------------------------------------------------------
__global__ __launch_bounds__(CS_THREADS) void scan_scatter_kernel(
    const int* __restrict__ edge_index,   // [2,E]
    int* __restrict__ counts,             // [N]
    int* __restrict__ offsets,            // [N+1]
    int* __restrict__ cursors,            // [N]
    int* __restrict__ blocksums,          // [CS_BLOCKS]
    int* __restrict__ cols,               // [E]
    int* __restrict__ eperm,              // [E]
    int N, int E)
{
    cg::grid_group grid = cg::this_grid();
    __shared__ int tmp[CS_THREADS];
    const int t   = threadIdx.x;
    const int gid = blockIdx.x * CS_THREADS + t;
    const int nth = CS_BLOCKS * CS_THREADS;

    // P0: zero counts
    if (gid < N) counts[gid] = 0;
    grid.sync();

    // P1: histogram
    for (int i = gid; i < E; i += nth)
        atomicAdd(&counts[edge_index[i]], 1);
    grid.sync();

    // P2: block-local inclusive scan of this block's 512-element chunk
    int v = (gid < N) ? counts[gid] : 0;
    tmp[t] = v;
    __syncthreads();
    for (int off = 1; off < CS_THREADS; off <<= 1) {
        int x = (t >= off) ? tmp[t - off] : 0;
        __syncthreads();
        tmp[t] += x;
        __syncthreads();
    }
    const int excl = tmp[t] - v;            // exclusive within block
    if (t == CS_THREADS - 1) blocksums[blockIdx.x] = tmp[t];
    grid.sync();

    // P3: block 0 scans the CS_BLOCKS partial sums (exclusive)
    if (blockIdx.x == 0) {
        int b = (t < CS_BLOCKS) ? blocksums[t] : 0;
        tmp[t] = b;
        __syncthreads();
        for (int off = 1; off < CS_THREADS; off <<= 1) {
            int x = (t >= off) ? tmp[t - off] : 0;
            __syncthreads();
            tmp[t] += x;
            __syncthreads();
        }
        if (t < CS_BLOCKS) blocksums[t] = tmp[t] - b;
    }
    grid.sync();

    // P4: offsets + cursors
    if (gid < N) {
        const int o = excl + blocksums[blockIdx.x];
        offsets[gid] = o;
        cursors[gid] = o;
    }
    if (gid == N) offsets[N] = E;
    grid.sync();

    // P5: scatter -- claim CSR slot p; record source col + forward perm
    for (int i = gid; i < E; i += nth) {
        const int r = edge_index[i];
        int p = atomicAdd(&cursors[r], 1);
        cols[p] = edge_index[E + i];
        eperm[p] = i;
    }
}

// ---------------------------------------------------------------------------
// Phase A (MFMA, CSR slot order): gathers edge_length rows via eperm
// (L3-resident -> FETCH 33 MB), writes W rows SEQUENTIALLY (125 MB, no
// write-allocate). NEW: W layout is INTERLEAVED {ws[c],wv[c]} pairs --
// m=0's output tile is retained in 16 x s16x4 registers and merged with
// m=1's tile at store time. Node then needs ONE dword load per lane/edge.
// ---------------------------------------------------------------------------
__global__ __launch_bounds__(256) void mlp_mfma_kernel(
    const float* __restrict__ edge_length,   // [E,32]
    const int*   __restrict__ eperm,         // [E] edge id at CSR slot p
    const float* __restrict__ sw1, const float* __restrict__ sb1,
    const float* __restrict__ sw2, const float* __restrict__ sb2,
    const float* __restrict__ vw1, const float* __restrict__ vb1,
    const float* __restrict__ vw2, const float* __restrict__ vb2,
    unsigned short* __restrict__ W,          // [E,128] bf16 interleaved pairs
    int E, int nchunks)
{
    __shared__ short Hs[4][64 * HSTR];       // per-wave staging

    const int t    = threadIdx.x;
    const int lane = t & 63;
    const int wid  = t >> 6;
    const int quad = lane >> 4;
    const int l16  = lane & 15;
    short* Hw = Hs[wid];

    const float* w1p[2] = {sw1, vw1};
    const float* b1p[2] = {sb1, vb1};
    const float* w2p[2] = {sw2, vw2};
    const float* b2p[2] = {sb2, vb2};

    // ---- weight B-frags resident in VGPRs ----
    bf16x8 w1f[2][4];
    bf16x8 w2f[2][2][4];
    float  b1v[2][4], b2v[2][4];
    #pragma unroll
    for (int m = 0; m < 2; ++m) {
        #pragma unroll
        for (int nt = 0; nt < 4; ++nt) {
            const int col = nt * 16 + l16;
            #pragma unroll
            for (int j = 0; j < 8; ++j)
                w1f[m][nt][j] = (short)f2bf(w1p[m][(quad * 8 + j) * HIDDEN + col]);
            #pragma unroll
            for (int kk = 0; kk < 2; ++kk) {
                #pragma unroll
                for (int j = 0; j < 8; ++j)
                    w2f[m][kk][nt][j] = (short)f2bf(w2p[m][(kk * 32 + quad * 8 + j) * HIDDEN + col]);
            }
            b1v[m][nt] = b1p[m][col];
            b2v[m][nt] = b2p[m][col];
        }
    }

    const int wave_g = blockIdx.x * 4 + wid;
    const int nwaves = gridDim.x * 4;

    for (int c = wave_g; c < nchunks; c += nwaves) {
        const int j0 = c * 64;

        // ---- A-frags: 64 CSR slots -> gathered edge rows (L3-resident) ----
        bf16x8 af[4];
        #pragma unroll
        for (int mt = 0; mt < 4; ++mt) {
            int p = j0 + mt * 16 + l16;
            if (p >= E) p = E - 1;
            const int e = eperm[p];
            const float* r = edge_length + (size_t)e * NB + quad * 8;
            float4 u0 = *(const float4*)r;
            float4 u1 = *(const float4*)(r + 4);
            af[mt][0] = (short)f2bf(u0.x); af[mt][1] = (short)f2bf(u0.y);
            af[mt][2] = (short)f2bf(u0.z); af[mt][3] = (short)f2bf(u0.w);
            af[mt][4] = (short)f2bf(u1.x); af[mt][5] = (short)f2bf(u1.y);
            af[mt][6] = (short)f2bf(u1.z); af[mt][7] = (short)f2bf(u1.w);
        }

        s16x4 ssav[16];   // m=0 (scalar-MLP) output tile, store-order mapping

        #pragma unroll
        for (int m = 0; m < 2; ++m) {
            // ---- layer 1 + SiLU -> LDS bf16 ----
            #pragma unroll
            for (int mt = 0; mt < 4; ++mt) {
                #pragma unroll
                for (int nt = 0; nt < 4; ++nt) {
                    f32x4 cf = {b1v[m][nt], b1v[m][nt], b1v[m][nt], b1v[m][nt]};
                    cf = __builtin_amdgcn_mfma_f32_16x16x32_bf16(af[mt], w1f[m][nt], cf, 0, 0, 0);
                    #pragma unroll
                    for (int r4 = 0; r4 < 4; ++r4) {
                        float x = cf[r4];
                        // silu via fast rcp: result is rounded to bf16 anyway
                        x = x * __builtin_amdgcn_rcpf(1.0f + __expf(-x));
                        const int row = mt * 16 + quad * 4 + r4;
                        Hw[row * HSTR + nt * 16 + l16] = (short)f2bf(x);
                    }
                }
            }

            // ---- layer 2 -> LDS bf16 ----
            #pragma unroll
            for (int mt = 0; mt < 4; ++mt) {
                const int arow = mt * 16 + l16;
                bf16x8 a0 = *(const bf16x8*)(Hw + arow * HSTR + quad * 8);
                bf16x8 a1 = *(const bf16x8*)(Hw + arow * HSTR + 32 + quad * 8);
                #pragma unroll
                for (int nt = 0; nt < 4; ++nt) {
                    f32x4 cf = {b2v[m][nt], b2v[m][nt], b2v[m][nt], b2v[m][nt]};
                    cf = __builtin_amdgcn_mfma_f32_16x16x32_bf16(a1, w2f[m][1][nt], cf, 0, 0, 0);
                    cf = __builtin_amdgcn_mfma_f32_16x16x32_bf16(a0, w2f[m][0][nt], cf, 0, 0, 0);
                    #pragma unroll
                    for (int r4 = 0; r4 < 4; ++r4) {
                        const int row = mt * 16 + quad * 4 + r4;
                        Hw[row * HSTR + nt * 16 + l16] = (short)f2bf(cf[r4]);
                    }
                }
            }

            // ---- m=0: save s-tile to regs; m=1: interleave + store ----
            // mapping: iteration i covers rows i*4+(lane>>4); lane's 4-col
            // slice c0=(lane&15)*4 (8 B ds_read_b64, conflict-light).
            if (m == 0) {
                #pragma unroll
                for (int i = 0; i < 16; ++i) {
                    const int row = i * 4 + (lane >> 4);
                    ssav[i] = *(const s16x4*)(Hw + row * HSTR + (lane & 15) * 4);
                }
            } else {
                #pragma unroll
                for (int i = 0; i < 16; ++i) {
                    const int row = i * 4 + (lane >> 4);
                    const s16x4 vv = *(const s16x4*)(Hw + row * HSTR + (lane & 15) * 4);
                    const s16x4 sv = ssav[i];
                    bf16x8 o;
                    o[0] = sv[0]; o[1] = vv[0];
                    o[2] = sv[1]; o[3] = vv[1];
                    o[4] = sv[2]; o[5] = vv[2];
                    o[6] = sv[3]; o[7] = vv[3];
                    if (j0 + row < E)
                        *(bf16x8*)(W + (size_t)(j0 + row) * 128 + (lane & 15) * 8) = o;
                }
            }
        }
    }
}

// ---------------------------------------------------------------------------
// Phase B (bf16 feat path): one wave per node; 1-ahead prefetch, chase-free
// cols (chunk-coalesced load + __shfl broadcast). NEW: interleaved W row ->
// one dword load per lane per edge ({ws,wv} unpacked with 1 shl + 1 and).
// ---------------------------------------------------------------------------
__global__ __launch_bounds__(256) void node_kernel_feat(
    const ushort4* __restrict__ feat,       // [N*64] bf16 {s,v0,v1,v2}
    const int* __restrict__ offsets,        // [N+1]
    const int* __restrict__ cols,           // [E] source column per CSR slot
    const unsigned short* __restrict__ W,   // [E,128] bf16 interleaved pairs
    float* __restrict__ out_scalar,
    float* __restrict__ out_vector,
    int N)
{
    const int lane = threadIdx.x & 63;
    const int wave = blockIdx.x * 4 + (threadIdx.x >> 6);
    const int nw   = gridDim.x * 4;

    for (int n = wave; n < N; n += nw) {
        const int beg = offsets[n];
        const int end = offsets[n + 1];

        float as = 0.0f, a0 = 0.0f, a1 = 0.0f, a2 = 0.0f;

        for (int base = beg; base < end; base += 64) {
            const int cnt = (end - base < 64) ? (end - base) : 64;

            // one coalesced load per chunk: lane's CSR column
            int mycol = 0;
            if (lane < cnt) mycol = cols[base + lane];

            // prologue: edge k=0
            const int c0 = __shfl(mycol, 0, 64);
            unsigned wu = ((const unsigned*)(W + (size_t)base * 128))[lane];
            ushort4 f = feat[(size_t)c0 * 64 + lane];

            for (int k = 0; k < cnt; ++k) {
                const int kn = (k + 1 < cnt) ? k + 1 : k;
                const int cn = __shfl(mycol, kn, 64);
                const unsigned wun =
                    ((const unsigned*)(W + (size_t)(base + kn) * 128))[lane];
                const ushort4 fn = feat[(size_t)cn * 64 + lane];

                const float ws = lo_bf(wu);
                const float wv = hi_bf(wu);
                as = fmaf(bf2f(f.x), ws, as);
                a0 = fmaf(bf2f(f.y), wv, a0);
                a1 = fmaf(bf2f(f.z), wv, a1);
                a2 = fmaf(bf2f(f.w), wv, a2);

                wu = wun; f = fn;
            }
        }

        out_scalar[(size_t)n * HIDDEN + lane] = as;
        float* ov = out_vector + (size_t)n * 3 * HIDDEN;
        ov[lane]       = a0;
        ov[64 + lane]  = a1;
        ov[128 + lane] = a2;
    }
}

// Fallback (fp32 feature gathers) if workspace can't hold the feat table.
__global__ __launch_bounds__(256) void node_kernel_f32(
    const float* __restrict__ scalar,
    const float* __restrict__ vector,
    const int* __restrict__ offsets,
    const int* __restrict__ cols,
    const unsigned short* __restrict__ W,   // interleaved pairs
    float* __restrict__ out_scalar,
    float* __restrict__ out_vector,
    int N)
{
    const int lane = threadIdx.x & 63;
    const int wave = blockIdx.x * 4 + (threadIdx.x >> 6);
    const int nw   = gridDim.x * 4;

    for (int n = wave; n < N; n += nw) {
        const int beg = offsets[n];
        const int end = offsets[n + 1];
        float as = 0.0f, a0 = 0.0f, a1 = 0.0f, a2 = 0.0f;
        for (int j = beg; j < end; ++j) {
            const unsigned wu = ((const unsigned*)(W + (size_t)j * 128))[lane];
            const float w_s = lo_bf(wu);
            const float w_v = hi_bf(wu);
            const int c = cols[j];
            const float* sp = scalar + (size_t)c * HIDDEN;
            const float* vp = vector + (size_t)c * 3 * HIDDEN;
            as = fmaf(sp[lane],       w_s, as);
            a0 = fmaf(vp[lane],       w_v, a0);
            a1 = fmaf(vp[64 + lane],  w_v, a1);
            a2 = fmaf(vp[128 + lane], w_v, a2);
        }
        out_scalar[(size_t)n * HIDDEN + lane] = as;
        float* ov = out_vector + (size_t)n * 3 * HIDDEN;
        ov[lane]       = a0;
        ov[64 + lane]  = a1;
        ov[128 + lane] = a2;
    }
}

extern "C" void kernel_launch(void* const* d_in, const int* in_sizes, int n_in,
                              void* d_out, int out_size, void* d_ws, size_t ws_size,
                              hipStream_t stream) {
    const float* scalar      = (const float*)d_in[0];
    const float* vector      = (const float*)d_in[1];
    // d_in[2] = edge_sh (unused by reference)
    const float* edge_length = (const float*)d_in[3];
    const int*   edge_index  = (const int*)d_in[4];
    const float* sw1 = (const float*)d_in[5];
    const float* sb1 = (const float*)d_in[6];
    const float* sw2 = (const float*)d_in[7];
    const float* sb2 = (const float*)d_in[8];
    const float* vw1 = (const float*)d_in[9];
    const float* vb1 = (const float*)d_in[10];
    const float* vw2 = (const float*)d_in[11];
    const float* vb2 = (const float*)d_in[12];

    const int N = in_sizes[0] / HIDDEN;       // 50000
    const int E = in_sizes[4] / 2;            // 500000

    float* out_scalar = (float*)d_out;
    float* out_vector = (float*)d_out + (size_t)N * HIDDEN;

    // ---- workspace layout ----
    size_t off = 0;
    unsigned short* W = (unsigned short*)d_ws;           // [E,128] bf16 = 128 MB
    off += (size_t)E * 128 * 2;
    int* cols = (int*)((char*)d_ws + off);               // [E]
    off += (size_t)E * 4;
    int* eperm = (int*)((char*)d_ws + off);              // [E]
    off += (size_t)E * 4;
    int* ib = (int*)((char*)d_ws + off);
    int* counts    = ib;                                  // [N]
    int* offsets   = ib + N;                              // [N+1]
    int* cursors   = ib + 2 * N + 1;                      // [N]
    int* blocksums = ib + 3 * N + 1;                      // [CS_BLOCKS]
    off += ((size_t)3 * N + 1 + CS_BLOCKS) * 4;
    off = (off + 15) & ~(size_t)15;
    ushort4* feat = (ushort4*)((char*)d_ws + off);        // [N*64] = 25.6 MB
    const bool use_feat = (off + (size_t)N * 64 * 8) <= ws_size;

    const int total = N * 64;

    // featpack (pure pack; x2 vectorized)
    if (use_feat) {
        const int nthreads = total / 2;                   // total is even
        featpack_kernel<<<(nthreads + 255) / 256, 256, 0, stream>>>(
            scalar, vector, (u16x8*)feat, total);
    }

    // zero + hist + scan + scatter in ONE cooperative dispatch
    {
        void* args[] = {
            (void*)&edge_index, (void*)&counts, (void*)&offsets,
            (void*)&cursors, (void*)&blocksums, (void*)&cols, (void*)&eperm,
            (void*)&N, (void*)&E
        };
        hipLaunchCooperativeKernel((void*)scan_scatter_kernel,
                                   dim3(CS_BLOCKS), dim3(CS_THREADS),
                                   args, 0, stream);
    }

    // Phase A: MLP via MFMA over CSR slots; gathered reads, sequential
    // interleaved-pair writes.
    const int nchunks = (E + 63) / 64;
    mlp_mfma_kernel<<<1024, 256, 0, stream>>>(
        edge_length, eperm,
        sw1, sb1, sw2, sb2, vw1, vb1, vw2, vb2,
        W, E, nchunks);

    // Phase B: sequential W streaming (1 dword/lane/edge), chase-free gathers.
    const int ngrid = (N + 3) / 4;
    if (use_feat) {
        node_kernel_feat<<<ngrid, 256, 0, stream>>>(
            feat, offsets, cols, W, out_scalar, out_vector, N);
    } else {
        node_kernel_f32<<<ngrid, 256, 0, stream>>>(
            scalar, vector, offsets, cols, W, out_scalar, out_vector, N);
    }
}